// Round 1
// baseline (823.964 us; speedup 1.0000x reference)
//
#include <hip/hip_runtime.h>
#include <hip/hip_bf16.h>

#define FEAT 128
#define NRELS 8

typedef __bf16 bf16_t;
typedef __bf16 bf16x2_t __attribute__((ext_vector_type(2)));
typedef __bf16 bf16x4_t __attribute__((ext_vector_type(4)));
typedef __bf16 bf16x8_t __attribute__((ext_vector_type(8)));
typedef float f32x4 __attribute__((ext_vector_type(4)));

// ---------------------------------------------------------------------------
// Convert weight [R][d][f] fp32 -> Wt [R][f][d] bf16 (transposed so MFMA
// B-fragments -- contiguous k=d per lane -- are 16B vector loads).
__global__ void k_convert_w(const float* __restrict__ w, bf16_t* __restrict__ wt) {
    int i = blockIdx.x * blockDim.x + threadIdx.x;
    if (i >= NRELS * FEAT * FEAT) return;
    int r = i >> 14;
    int rem = i & 16383;
    int d = rem >> 7;
    int f = rem & 127;
    wt[(r << 14) + (f << 7) + d] = (bf16_t)w[i];
}

// ---------------------------------------------------------------------------
// h fp32 -> bf16, vectorized (float4 in, bf16x4 out)
__global__ void k_convert_h(const float* __restrict__ h, bf16x4_t* __restrict__ hb4,
                            int node0, int total4) {
    int i = blockIdx.x * blockDim.x + threadIdx.x;
    if (i >= total4) return;
    float4 v = reinterpret_cast<const float4*>(h)[(size_t)node0 * (FEAT / 4) + i];
    bf16x4_t o;
    o.x = (bf16_t)v.x; o.y = (bf16_t)v.y; o.z = (bf16_t)v.z; o.w = (bf16_t)v.w;
    hb4[i] = o;
}

// ---------------------------------------------------------------------------
// Gate: sig_gate[n][r] = sigmoid(sum_d h[n][d] * gw[r][d]); fp32 throughout.
// One wave per node; butterfly shuffle reduce per relation.
__global__ void k_gate(const float* __restrict__ h, const float* __restrict__ gw,
                       float* __restrict__ sg, int node0, int ncount) {
    int wv = (int)((blockIdx.x * blockDim.x + threadIdx.x) >> 6);
    int lane = threadIdx.x & 63;
    if (wv >= ncount) return;
    int node = node0 + wv;
    float2 hv = *reinterpret_cast<const float2*>(h + (size_t)node * FEAT + lane * 2);
    float res[NRELS];
#pragma unroll
    for (int r = 0; r < NRELS; ++r) {
        float2 wvv = *reinterpret_cast<const float2*>(gw + r * FEAT + lane * 2);
        float s = hv.x * wvv.x + hv.y * wvv.y;
#pragma unroll
        for (int off = 32; off; off >>= 1) s += __shfl_xor(s, off, 64);
        res[r] = s;
    }
    if (lane == 0) {
#pragma unroll
        for (int r = 0; r < NRELS; ++r)
            sg[(size_t)wv * NRELS + r] = 1.0f / (1.0f + __expf(-res[r]));
    }
}

// ---------------------------------------------------------------------------
// GEMM: hall[n][r][f] = sum_d hb[n][d] * W[r][d][f]   (bf16 in, fp32 acc, bf16 out)
// Block = 256 threads (4 waves), computes a [128 node x 128 f] tile for one r.
// Wave w handles rows [w*32, w*32+32): 2 (tm) x 8 (tn) mfma_16x16x32 tiles, K=128
// in 4 k-steps. Operands streamed from global (h chunk + 32KB Wt[r] stay L1/L2 hot).
__global__ __launch_bounds__(256) void k_gemm(const bf16_t* __restrict__ hb,
                                              const bf16_t* __restrict__ wt,
                                              bf16_t* __restrict__ hall,
                                              int ncount) {
    const int tile = blockIdx.x;
    const int r = blockIdx.y;
    const int wv = threadIdx.x >> 6;
    const int lane = threadIdx.x & 63;
    const int l15 = lane & 15;
    const int lhi = lane >> 4;

    const int m_base = tile * 128 + wv * 32;

    // A-fragments: A[m = lane&15][k = (lane>>4)*8 + j]  (m89-verified layout)
    bf16x8_t afrag[2][4];
#pragma unroll
    for (int tm = 0; tm < 2; ++tm) {
        int row = m_base + tm * 16 + l15;
        row = row < ncount ? row : ncount - 1;  // clamp; stores are masked
        const bf16_t* ap = hb + (size_t)row * FEAT + lhi * 8;
#pragma unroll
        for (int ks = 0; ks < 4; ++ks)
            afrag[tm][ks] = *reinterpret_cast<const bf16x8_t*>(ap + ks * 32);
    }

    f32x4 acc[2][8];
#pragma unroll
    for (int tm = 0; tm < 2; ++tm)
#pragma unroll
        for (int tn = 0; tn < 8; ++tn)
            acc[tm][tn] = (f32x4){0.f, 0.f, 0.f, 0.f};

#pragma unroll
    for (int ks = 0; ks < 4; ++ks) {
        // B-fragments: B[k][n], n = lane&15, k = (lane>>4)*8 + j -> Wt[r][n][k] contiguous
        bf16x8_t bfrag[8];
#pragma unroll
        for (int tn = 0; tn < 8; ++tn) {
            const bf16_t* bp = wt + ((size_t)r << 14) +
                               (size_t)(tn * 16 + l15) * FEAT + ks * 32 + lhi * 8;
            bfrag[tn] = *reinterpret_cast<const bf16x8_t*>(bp);
        }
#pragma unroll
        for (int tn = 0; tn < 8; ++tn)
#pragma unroll
            for (int tm = 0; tm < 2; ++tm)
                acc[tm][tn] = __builtin_amdgcn_mfma_f32_16x16x32_bf16(
                    afrag[tm][ks], bfrag[tn], acc[tm][tn], 0, 0, 0);
    }

    // C/D layout: col = lane&15, row = (lane>>4)*4 + reg (m89/m91-verified)
#pragma unroll
    for (int tm = 0; tm < 2; ++tm) {
#pragma unroll
        for (int i = 0; i < 4; ++i) {
            int row = m_base + tm * 16 + lhi * 4 + i;
            if (row < ncount) {
                bf16_t* op = hall + ((size_t)row * NRELS + r) * FEAT + l15;
#pragma unroll
                for (int tn = 0; tn < 8; ++tn)
                    op[tn * 16] = (bf16_t)acc[tm][tn][i];
            }
        }
    }
}

// ---------------------------------------------------------------------------
// Edge scatter: one wave per edge. Lane i handles features 2i, 2i+1.
__global__ __launch_bounds__(256) void k_scatter(const bf16_t* __restrict__ hall,
                                                 const float* __restrict__ sg,
                                                 const float* __restrict__ nrm,
                                                 const int* __restrict__ src,
                                                 const int* __restrict__ dstv,
                                                 const int* __restrict__ rel,
                                                 float* __restrict__ out,
                                                 int node0, int ncount, int nedges) {
    int e = (int)((blockIdx.x * blockDim.x + threadIdx.x) >> 6);
    if (e >= nedges) return;
    int lane = threadIdx.x & 63;
    int s = src[e] - node0;
    if ((unsigned)s >= (unsigned)ncount) return;  // other chunk handles it
    int r = rel[e];
    float scale = nrm[e] * sg[(size_t)s * NRELS + r];
    bf16x2_t mv = *reinterpret_cast<const bf16x2_t*>(
        hall + ((size_t)s * NRELS + r) * FEAT + lane * 2);
    float* op = out + (size_t)dstv[e] * FEAT + lane * 2;
    unsafeAtomicAdd(op, (float)mv.x * scale);
    unsafeAtomicAdd(op + 1, (float)mv.y * scale);
}

// ---------------------------------------------------------------------------
__global__ void k_relu(float4* __restrict__ out, int total4) {
    int i = blockIdx.x * blockDim.x + threadIdx.x;
    if (i >= total4) return;
    float4 v = out[i];
    v.x = fmaxf(v.x, 0.f);
    v.y = fmaxf(v.y, 0.f);
    v.z = fmaxf(v.z, 0.f);
    v.w = fmaxf(v.w, 0.f);
    out[i] = v;
}

// ---------------------------------------------------------------------------
extern "C" void kernel_launch(void* const* d_in, const int* in_sizes, int n_in,
                              void* d_out, int out_size, void* d_ws, size_t ws_size,
                              hipStream_t stream) {
    const float* h = (const float*)d_in[0];
    const float* w = (const float*)d_in[1];
    const float* gw = (const float*)d_in[2];
    const float* nrm = (const float*)d_in[3];
    const int* src = (const int*)d_in[4];
    const int* dst = (const int*)d_in[5];
    const int* rel = (const int*)d_in[6];
    float* out = (float*)d_out;

    const int N = in_sizes[0] / FEAT;
    const int E = in_sizes[4];

    char* ws = (char*)d_ws;
    size_t off = 0;
    bf16_t* wt = (bf16_t*)ws;
    off += (size_t)NRELS * FEAT * FEAT * sizeof(bf16_t);  // 256 KiB

    // Chunk nodes so all per-node buffers fit ws (ws_size is constant across
    // calls, so the chunk count -- and thus the captured graph -- is too).
    const size_t per_node = FEAT * sizeof(bf16_t)                 // hb
                          + NRELS * sizeof(float)                 // sig gate
                          + (size_t)NRELS * FEAT * sizeof(bf16_t);// hall
    size_t avail = ws_size > off ? ws_size - off : 0;
    long long cmax = (long long)(avail / per_node);
    int C = (int)((cmax / 128) * 128);
    int Nceil = ((N + 127) / 128) * 128;
    if (C > Nceil) C = Nceil;
    if (C < 128) C = 128;

    bf16_t* hb = (bf16_t*)(ws + off);
    off += (size_t)C * FEAT * sizeof(bf16_t);
    float* sg = (float*)(ws + off);
    off += (size_t)C * NRELS * sizeof(float);
    bf16_t* hall = (bf16_t*)(ws + off);

    hipMemsetAsync(d_out, 0, (size_t)N * FEAT * sizeof(float), stream);
    k_convert_w<<<(NRELS * FEAT * FEAT + 255) / 256, 256, 0, stream>>>(w, wt);

    for (int node0 = 0; node0 < N; node0 += C) {
        int nc = N - node0;
        if (nc > C) nc = C;
        int total4 = nc * (FEAT / 4);
        k_convert_h<<<(total4 + 255) / 256, 256, 0, stream>>>(h, (bf16x4_t*)hb, node0, total4);
        k_gate<<<(nc + 3) / 4, 256, 0, stream>>>(h, gw, sg, node0, nc);
        dim3 gg((nc + 127) / 128, NRELS);
        k_gemm<<<gg, 256, 0, stream>>>(hb, wt, hall, nc);
        k_scatter<<<(E + 3) / 4, 256, 0, stream>>>(hall, sg, nrm, src, dst, rel, out,
                                                   node0, nc, E);
    }
    k_relu<<<((N * FEAT / 4) + 255) / 256, 256, 0, stream>>>((float4*)out, N * FEAT / 4);
}

// Round 2
// 479.925 us; speedup vs baseline: 1.7169x; 1.7169x over previous
//
#include <hip/hip_runtime.h>
#include <hip/hip_bf16.h>

#define FEAT 128
#define NRELS 8
#define SCAN_CHUNK 4096

typedef __bf16 bf16_t;
typedef __bf16 bf16x2_t __attribute__((ext_vector_type(2)));
typedef __bf16 bf16x4_t __attribute__((ext_vector_type(4)));
typedef __bf16 bf16x8_t __attribute__((ext_vector_type(8)));
typedef float f32x4 __attribute__((ext_vector_type(4)));

struct __align__(8) PackedEdge { int row; float scale; };

static inline size_t align256(size_t x) { return (x + 255) & ~(size_t)255; }

// ---------------------------------------------------------------------------
// Weight [R][d][f] fp32 -> Wt [R][f][d] bf16 (transposed: MFMA fragments need
// contiguous k=d per lane -> 16B vector loads).
__global__ void k_convert_w(const float* __restrict__ w, bf16_t* __restrict__ wt) {
    int i = blockIdx.x * blockDim.x + threadIdx.x;
    if (i >= NRELS * FEAT * FEAT) return;
    int r = i >> 14;
    int rem = i & 16383;
    int d = rem >> 7;
    int f = rem & 127;
    wt[(r << 14) + (f << 7) + d] = (bf16_t)w[i];
}

// ---------------------------------------------------------------------------
// h fp32 -> bf16. Reads h rows [node0, node0+nvalid), writes hb rows
// [0, ntotal) with zero padding for rows >= nvalid (tail tiles).
__global__ void k_convert_h(const float* __restrict__ h, bf16x4_t* __restrict__ hb4,
                            int node0, int nvalid, int ntotal) {
    int i = blockIdx.x * blockDim.x + threadIdx.x;
    if (i >= ntotal * (FEAT / 4)) return;
    int localnode = i >> 5;
    bf16x4_t o = (bf16x4_t){(bf16_t)0.f, (bf16_t)0.f, (bf16_t)0.f, (bf16_t)0.f};
    if (localnode < nvalid) {
        float4 v = reinterpret_cast<const float4*>(h)[(size_t)(node0 + localnode) * (FEAT / 4) + (i & 31)];
        o.x = (bf16_t)v.x; o.y = (bf16_t)v.y; o.z = (bf16_t)v.z; o.w = (bf16_t)v.w;
    }
    hb4[i] = o;
}

// ---------------------------------------------------------------------------
// Gate: sg[n][r] = sigmoid(sum_d h[n][d]*gw[r][d]); fp32. One wave per node.
__global__ void k_gate(const float* __restrict__ h, const float* __restrict__ gw,
                       float* __restrict__ sg, int node0, int ncount) {
    int wv = (int)((blockIdx.x * blockDim.x + threadIdx.x) >> 6);
    int lane = threadIdx.x & 63;
    if (wv >= ncount) return;
    float2 hv = *reinterpret_cast<const float2*>(h + (size_t)(node0 + wv) * FEAT + lane * 2);
    float res[NRELS];
#pragma unroll
    for (int r = 0; r < NRELS; ++r) {
        float2 wvv = *reinterpret_cast<const float2*>(gw + r * FEAT + lane * 2);
        float s = hv.x * wvv.x + hv.y * wvv.y;
#pragma unroll
        for (int off = 32; off; off >>= 1) s += __shfl_xor(s, off, 64);
        res[r] = s;
    }
    if (lane == 0) {
#pragma unroll
        for (int r = 0; r < NRELS; ++r)
            sg[(size_t)wv * NRELS + r] = 1.0f / (1.0f + __expf(-res[r]));
    }
}

// ---------------------------------------------------------------------------
// GEMM with swapped roles: M=f, N=node.  D[f][node] = sum_d Wt[r][f][d]*hb[node][d].
// Block = 4 waves = [128 f x 128 nodes] for one r. C/D layout: col(lane&15)=node,
// row(lhi*4+i)=f -> each lane holds 4 consecutive f => bf16x4 vector stores.
__global__ __launch_bounds__(256) void k_gemm(const bf16_t* __restrict__ hb,
                                              const bf16_t* __restrict__ wt,
                                              bf16_t* __restrict__ hall) {
    const int r = blockIdx.x;          // fastest -> 8 consecutive blocks share hb tile in L2
    const int tile = blockIdx.y;
    const int wv = threadIdx.x >> 6;
    const int lane = threadIdx.x & 63;
    const int l15 = lane & 15;
    const int lhi = lane >> 4;

    const int f_base = wv * 32;        // wave covers f in [f_base, f_base+32)

    // A-fragments from Wt[r]: A[m=f=lane&15 offset][k = ks*32 + lhi*8 + j]
    bf16x8_t afrag[2][4];
#pragma unroll
    for (int tm = 0; tm < 2; ++tm) {
        const bf16_t* ap = wt + ((size_t)r << 14) + (size_t)(f_base + tm * 16 + l15) * FEAT + lhi * 8;
#pragma unroll
        for (int ks = 0; ks < 4; ++ks)
            afrag[tm][ks] = *reinterpret_cast<const bf16x8_t*>(ap + ks * 32);
    }

    f32x4 acc[2][8];
#pragma unroll
    for (int tm = 0; tm < 2; ++tm)
#pragma unroll
        for (int tn = 0; tn < 8; ++tn)
            acc[tm][tn] = (f32x4){0.f, 0.f, 0.f, 0.f};

#pragma unroll
    for (int ks = 0; ks < 4; ++ks) {
        // B-fragments from hb: B[k][n=node=lane&15 offset], k contiguous per lane
        bf16x8_t bfrag[8];
#pragma unroll
        for (int tn = 0; tn < 8; ++tn) {
            const bf16_t* bp = hb + (size_t)(tile * 128 + tn * 16 + l15) * FEAT + ks * 32 + lhi * 8;
            bfrag[tn] = *reinterpret_cast<const bf16x8_t*>(bp);
        }
#pragma unroll
        for (int tn = 0; tn < 8; ++tn)
#pragma unroll
            for (int tm = 0; tm < 2; ++tm)
                acc[tm][tn] = __builtin_amdgcn_mfma_f32_16x16x32_bf16(
                    afrag[tm][ks], bfrag[tn], acc[tm][tn], 0, 0, 0);
    }

    // Store: node = tile*128 + tn*16 + l15; f = f_base + tm*16 + lhi*4 + i
#pragma unroll
    for (int tm = 0; tm < 2; ++tm) {
        int f0 = f_base + tm * 16 + lhi * 4;
#pragma unroll
        for (int tn = 0; tn < 8; ++tn) {
            int node = tile * 128 + tn * 16 + l15;
            bf16x4_t o;
            o.x = (bf16_t)acc[tm][tn][0];
            o.y = (bf16_t)acc[tm][tn][1];
            o.z = (bf16_t)acc[tm][tn][2];
            o.w = (bf16_t)acc[tm][tn][3];
            *reinterpret_cast<bf16x4_t*>(hall + ((size_t)node * NRELS + r) * FEAT + f0) = o;
        }
    }
}

// ---------------------------------------------------------------------------
// CSR build
__global__ void k_degree(const int* __restrict__ dstv, int* __restrict__ deg, int nedges) {
    int e = blockIdx.x * blockDim.x + threadIdx.x;
    if (e >= nedges) return;
    atomicAdd(&deg[dstv[e]], 1);
}

__global__ __launch_bounds__(256) void k_scan_block(const int* __restrict__ in,
                                                    int* __restrict__ outv,
                                                    int* __restrict__ bsum, int n) {
    __shared__ int sm[256];
    __shared__ int carry;
    int t = threadIdx.x;
    if (t == 0) carry = 0;
    __syncthreads();
    int base = blockIdx.x * SCAN_CHUNK;
#pragma unroll 1
    for (int it = 0; it < SCAN_CHUNK / 256; ++it) {
        int idx = base + it * 256 + t;
        int v = (idx < n) ? in[idx] : 0;
        sm[t] = v;
        __syncthreads();
        for (int off = 1; off < 256; off <<= 1) {
            int x = (t >= off) ? sm[t - off] : 0;
            __syncthreads();
            sm[t] += x;
            __syncthreads();
        }
        int incl = sm[t];
        int ex = incl - v + carry;
        if (idx < n) outv[idx] = ex;
        __syncthreads();
        if (t == 255) carry += incl;   // incl at t=255 == chunk total
        __syncthreads();
    }
    if (t == 0) bsum[blockIdx.x] = carry;
}

__global__ void k_scan_tops(int* __restrict__ bsum, int nb, int* __restrict__ rowptr_end) {
    if (blockIdx.x == 0 && threadIdx.x == 0) {
        int run = 0;
        for (int b = 0; b < nb; ++b) { int v = bsum[b]; bsum[b] = run; run += v; }
        *rowptr_end = run;   // rowptr[N] = E
    }
}

__global__ void k_scan_add(int* __restrict__ rowptr, const int* __restrict__ bsum, int n) {
    int i = blockIdx.x * blockDim.x + threadIdx.x;
    if (i >= n) return;
    rowptr[i] += bsum[i >> 12];   // 4096 = 1<<12
}

// Fill packed edge records {hall_row, norm*sigmoid_gate} at CSR slots.
__global__ void k_fill(const int* __restrict__ src, const int* __restrict__ dstv,
                       const int* __restrict__ rel, const float* __restrict__ nrm,
                       const float* __restrict__ sg, const int* __restrict__ rowptr,
                       int* __restrict__ cursor, PackedEdge* __restrict__ packed,
                       int nedges) {
    int e = blockIdx.x * blockDim.x + threadIdx.x;
    if (e >= nedges) return;
    int d = dstv[e];
    int s = src[e];
    int r = rel[e];
    int pos = rowptr[d] + atomicAdd(&cursor[d], 1);
    PackedEdge p;
    p.row = s * NRELS + r;
    p.scale = nrm[e] * sg[(size_t)s * NRELS + r];
    packed[pos] = p;
}

// ---------------------------------------------------------------------------
// Gather: one wave per dst node, register accumulate, fused ReLU, single write.
__global__ __launch_bounds__(256) void k_gather(const bf16_t* __restrict__ hall,
                                                const PackedEdge* __restrict__ packed,
                                                const int* __restrict__ rowptr,
                                                float* __restrict__ out, int nnodes) {
    int wv = (int)((blockIdx.x * blockDim.x + threadIdx.x) >> 6);
    int lane = threadIdx.x & 63;
    if (wv >= nnodes) return;
    int beg = rowptr[wv];
    int end = rowptr[wv + 1];
    float ax = 0.f, ay = 0.f;
    PackedEdge p;
    if (beg < end) p = packed[beg];
    for (int j = beg; j < end; ++j) {
        PackedEdge pn;
        if (j + 1 < end) pn = packed[j + 1];          // prefetch next record
        bf16x2_t mv = *reinterpret_cast<const bf16x2_t*>(
            hall + (size_t)p.row * FEAT + lane * 2);
        ax += (float)mv.x * p.scale;
        ay += (float)mv.y * p.scale;
        p = pn;
    }
    float2 o;
    o.x = fmaxf(ax, 0.f);
    o.y = fmaxf(ay, 0.f);
    *reinterpret_cast<float2*>(out + (size_t)wv * FEAT + lane * 2) = o;
}

// ---------------------------------------------------------------------------
// Fallback path (small ws): chunked atomic scatter (round-1 style)
__global__ __launch_bounds__(256) void k_scatter(const bf16_t* __restrict__ hall,
                                                 const float* __restrict__ sg,
                                                 const float* __restrict__ nrm,
                                                 const int* __restrict__ src,
                                                 const int* __restrict__ dstv,
                                                 const int* __restrict__ rel,
                                                 float* __restrict__ out,
                                                 int node0, int ncount, int nedges) {
    int e = (int)((blockIdx.x * blockDim.x + threadIdx.x) >> 6);
    if (e >= nedges) return;
    int lane = threadIdx.x & 63;
    int s = src[e] - node0;
    if ((unsigned)s >= (unsigned)ncount) return;
    int r = rel[e];
    float scale = nrm[e] * sg[(size_t)s * NRELS + r];
    bf16x2_t mv = *reinterpret_cast<const bf16x2_t*>(
        hall + ((size_t)s * NRELS + r) * FEAT + lane * 2);
    float* op = out + (size_t)dstv[e] * FEAT + lane * 2;
    unsafeAtomicAdd(op, (float)mv.x * scale);
    unsafeAtomicAdd(op + 1, (float)mv.y * scale);
}

__global__ void k_relu(float4* __restrict__ out, int total4) {
    int i = blockIdx.x * blockDim.x + threadIdx.x;
    if (i >= total4) return;
    float4 v = out[i];
    v.x = fmaxf(v.x, 0.f);
    v.y = fmaxf(v.y, 0.f);
    v.z = fmaxf(v.z, 0.f);
    v.w = fmaxf(v.w, 0.f);
    out[i] = v;
}

// ---------------------------------------------------------------------------
extern "C" void kernel_launch(void* const* d_in, const int* in_sizes, int n_in,
                              void* d_out, int out_size, void* d_ws, size_t ws_size,
                              hipStream_t stream) {
    const float* h = (const float*)d_in[0];
    const float* w = (const float*)d_in[1];
    const float* gw = (const float*)d_in[2];
    const float* nrm = (const float*)d_in[3];
    const int* src = (const int*)d_in[4];
    const int* dst = (const int*)d_in[5];
    const int* rel = (const int*)d_in[6];
    float* out = (float*)d_out;

    const int N = in_sizes[0] / FEAT;
    const int E = in_sizes[4];
    const int Nceil = ((N + 127) / 128) * 128;
    const int nb = (N + SCAN_CHUNK - 1) / SCAN_CHUNK;

    char* ws = (char*)d_ws;
    const size_t wtB = (size_t)NRELS * FEAT * FEAT * sizeof(bf16_t);      // 256 KiB
    const size_t hallB = (size_t)Nceil * NRELS * FEAT * sizeof(bf16_t);   // 205 MB
    const size_t hbB = (size_t)Nceil * FEAT * sizeof(bf16_t);             // 25.6 MB
    // CSR block (aliases hb region; lifetimes disjoint: CSR is built after GEMM)
    const size_t sgB = align256((size_t)N * NRELS * sizeof(float));
    const size_t degB = align256((size_t)N * sizeof(int));
    const size_t rowB = align256((size_t)(N + 1) * sizeof(int));
    const size_t bsB = align256((size_t)nb * sizeof(int));
    const size_t pkB = align256((size_t)E * sizeof(PackedEdge));
    const size_t csrB = sgB + degB + rowB + bsB + pkB;                    // ~6 MB
    const size_t tailNeed = hbB > csrB ? hbB : csrB;

    if (wtB + hallB + tailNeed <= ws_size) {
        // ------------------ full-graph CSR path ------------------
        bf16_t* wt = (bf16_t*)ws;
        bf16_t* hall = (bf16_t*)(ws + wtB);
        char* tail = ws + wtB + hallB;
        bf16_t* hb = (bf16_t*)tail;
        float* sg = (float*)tail;
        int* deg = (int*)(tail + sgB);
        int* rowptr = (int*)(tail + sgB + degB);
        int* bsum = (int*)(tail + sgB + degB + rowB);
        PackedEdge* packed = (PackedEdge*)(tail + sgB + degB + rowB + bsB);

        k_convert_w<<<(NRELS * FEAT * FEAT + 255) / 256, 256, 0, stream>>>(w, wt);
        k_convert_h<<<(Nceil * (FEAT / 4) + 255) / 256, 256, 0, stream>>>(h, (bf16x4_t*)hb, 0, N, Nceil);
        dim3 gg(NRELS, Nceil / 128);
        k_gemm<<<gg, 256, 0, stream>>>(hb, wt, hall);
        // hb dead from here; CSR block aliases it
        k_gate<<<(N + 3) / 4, 256, 0, stream>>>(h, gw, sg, 0, N);
        hipMemsetAsync(deg, 0, (size_t)N * sizeof(int), stream);
        k_degree<<<(E + 255) / 256, 256, 0, stream>>>(dst, deg, E);
        k_scan_block<<<nb, 256, 0, stream>>>(deg, rowptr, bsum, N);
        k_scan_tops<<<1, 64, 0, stream>>>(bsum, nb, rowptr + N);
        k_scan_add<<<(N + 255) / 256, 256, 0, stream>>>(rowptr, bsum, N);
        hipMemsetAsync(deg, 0, (size_t)N * sizeof(int), stream);          // reuse as cursor
        k_fill<<<(E + 255) / 256, 256, 0, stream>>>(src, dst, rel, nrm, sg, rowptr, deg, packed, E);
        k_gather<<<(N + 3) / 4, 256, 0, stream>>>(hall, packed, rowptr, out, N);
    } else {
        // ------------------ chunked atomic fallback ------------------
        bf16_t* wt = (bf16_t*)ws;
        const size_t per_node = FEAT * sizeof(bf16_t) + NRELS * sizeof(float)
                              + (size_t)NRELS * FEAT * sizeof(bf16_t);
        size_t avail = ws_size > wtB ? ws_size - wtB : 0;
        long long cmax = (long long)(avail / per_node);
        int C = (int)((cmax / 128) * 128);
        if (C > Nceil) C = Nceil;
        if (C < 128) C = 128;
        bf16_t* hb = (bf16_t*)(ws + wtB);
        float* sg = (float*)(ws + wtB + (size_t)C * FEAT * sizeof(bf16_t));
        bf16_t* hall = (bf16_t*)((char*)sg + (size_t)C * NRELS * sizeof(float));

        hipMemsetAsync(d_out, 0, (size_t)N * FEAT * sizeof(float), stream);
        k_convert_w<<<(NRELS * FEAT * FEAT + 255) / 256, 256, 0, stream>>>(w, wt);
        for (int node0 = 0; node0 < N; node0 += C) {
            int nc = N - node0;
            if (nc > C) nc = C;
            int ncceil = ((nc + 127) / 128) * 128;
            k_convert_h<<<(ncceil * (FEAT / 4) + 255) / 256, 256, 0, stream>>>(
                h, (bf16x4_t*)hb, node0, nc, ncceil);
            k_gate<<<(nc + 3) / 4, 256, 0, stream>>>(h, gw, sg, node0, nc);
            dim3 gg(NRELS, ncceil / 128);
            k_gemm<<<gg, 256, 0, stream>>>(hb, wt, hall);
            k_scatter<<<(E + 3) / 4, 256, 0, stream>>>(hall, sg, nrm, src, dst, rel, out,
                                                       node0, nc, E);
        }
        k_relu<<<((N * FEAT / 4) + 255) / 256, 256, 0, stream>>>((float4*)out, N * FEAT / 4);
    }
}

// Round 3
// 408.681 us; speedup vs baseline: 2.0162x; 1.1743x over previous
//
#include <hip/hip_runtime.h>
#include <hip/hip_bf16.h>

#define FEAT 128
#define NRELS 8
#define SCAN_CHUNK 256

typedef __bf16 bf16_t;
typedef __bf16 bf16x2_t __attribute__((ext_vector_type(2)));
typedef __bf16 bf16x4_t __attribute__((ext_vector_type(4)));
typedef __bf16 bf16x8_t __attribute__((ext_vector_type(8)));
typedef float f32x4 __attribute__((ext_vector_type(4)));

struct __align__(8) PackedEdge { int row; float scale; };

static inline size_t align256(size_t x) { return (x + 255) & ~(size_t)255; }

// ---------------------------------------------------------------------------
// Weight [R][d][f] fp32 -> Wt [R][f][d] bf16 (transposed: MFMA A-fragments need
// contiguous k=d per lane -> 16B vector loads).
__global__ void k_convert_w(const float* __restrict__ w, bf16_t* __restrict__ wt) {
    int i = blockIdx.x * blockDim.x + threadIdx.x;
    if (i >= NRELS * FEAT * FEAT) return;
    int r = i >> 14;
    int rem = i & 16383;
    int d = rem >> 7;
    int f = rem & 127;
    wt[(r << 14) + (f << 7) + d] = (bf16_t)w[i];
}

// ---------------------------------------------------------------------------
// h fp32 -> bf16; rows >= nvalid zero-padded (tail tiles).
__global__ void k_convert_h(const float* __restrict__ h, bf16x4_t* __restrict__ hb4,
                            int node0, int nvalid, int ntotal) {
    int i = blockIdx.x * blockDim.x + threadIdx.x;
    if (i >= ntotal * (FEAT / 4)) return;
    int localnode = i >> 5;
    bf16x4_t o = (bf16x4_t){(bf16_t)0.f, (bf16_t)0.f, (bf16_t)0.f, (bf16_t)0.f};
    if (localnode < nvalid) {
        float4 v = reinterpret_cast<const float4*>(h)[(size_t)(node0 + localnode) * (FEAT / 4) + (i & 31)];
        o.x = (bf16_t)v.x; o.y = (bf16_t)v.y; o.z = (bf16_t)v.z; o.w = (bf16_t)v.w;
    }
    hb4[i] = o;
}

// ---------------------------------------------------------------------------
// Gate: sg[n][r] = sigmoid(sum_d h[n][d]*gw[r][d]); fp32. One wave per node.
__global__ void k_gate(const float* __restrict__ h, const float* __restrict__ gw,
                       float* __restrict__ sg, int node0, int ncount) {
    int wv = (int)((blockIdx.x * blockDim.x + threadIdx.x) >> 6);
    int lane = threadIdx.x & 63;
    if (wv >= ncount) return;
    float2 hv = *reinterpret_cast<const float2*>(h + (size_t)(node0 + wv) * FEAT + lane * 2);
    float res[NRELS];
#pragma unroll
    for (int r = 0; r < NRELS; ++r) {
        float2 wvv = *reinterpret_cast<const float2*>(gw + r * FEAT + lane * 2);
        float s = hv.x * wvv.x + hv.y * wvv.y;
#pragma unroll
        for (int off = 32; off; off >>= 1) s += __shfl_xor(s, off, 64);
        res[r] = s;
    }
    if (lane == 0) {
#pragma unroll
        for (int r = 0; r < NRELS; ++r)
            sg[(size_t)wv * NRELS + r] = 1.0f / (1.0f + __expf(-res[r]));
    }
}

// ---------------------------------------------------------------------------
// GEMM, all 8 relations per block. Block = 4 waves = one 128-node tile.
// B-fragments (hb) loaded ONCE into registers (128 VGPRs), reused across r.
// Per r: 8 A-fragment loads (Wt[r], L2-resident) -> 64 MFMAs -> 16 bf16x4 stores.
// M=f, N=node; C/D layout col(lane&15)=node, row(lhi*4+i)=f (m89-verified).
__global__ __launch_bounds__(256, 2) void k_gemm8(const bf16_t* __restrict__ hb,
                                                  const bf16_t* __restrict__ wt,
                                                  bf16_t* __restrict__ hall) {
    const int tile = blockIdx.x;
    const int wv = threadIdx.x >> 6;
    const int lane = threadIdx.x & 63;
    const int l15 = lane & 15;
    const int lhi = lane >> 4;
    const int f_base = wv * 32;   // wave covers f in [f_base, f_base+32)

    // B-fragments: B[k][n], n = tn*16 + l15, k = ks*32 + lhi*8 + j (contiguous)
    bf16x8_t bfrag[8][4];
    const bf16_t* hbase = hb + (size_t)tile * 128 * FEAT;
#pragma unroll
    for (int tn = 0; tn < 8; ++tn) {
        const bf16_t* bp = hbase + (size_t)(tn * 16 + l15) * FEAT + lhi * 8;
#pragma unroll
        for (int ks = 0; ks < 4; ++ks)
            bfrag[tn][ks] = *reinterpret_cast<const bf16x8_t*>(bp + ks * 32);
    }

#pragma unroll 1
    for (int r = 0; r < NRELS; ++r) {
        // A-fragments from Wt[r]: A[m=f][k], k contiguous per lane
        bf16x8_t afrag[2][4];
#pragma unroll
        for (int tm = 0; tm < 2; ++tm) {
            const bf16_t* ap = wt + ((size_t)r << 14) +
                               (size_t)(f_base + tm * 16 + l15) * FEAT + lhi * 8;
#pragma unroll
            for (int ks = 0; ks < 4; ++ks)
                afrag[tm][ks] = *reinterpret_cast<const bf16x8_t*>(ap + ks * 32);
        }

        f32x4 acc[2][8];
#pragma unroll
        for (int tm = 0; tm < 2; ++tm)
#pragma unroll
            for (int tn = 0; tn < 8; ++tn)
                acc[tm][tn] = (f32x4){0.f, 0.f, 0.f, 0.f};

#pragma unroll
        for (int ks = 0; ks < 4; ++ks)
#pragma unroll
            for (int tn = 0; tn < 8; ++tn)
#pragma unroll
                for (int tm = 0; tm < 2; ++tm)
                    acc[tm][tn] = __builtin_amdgcn_mfma_f32_16x16x32_bf16(
                        afrag[tm][ks], bfrag[tn][ks], acc[tm][tn], 0, 0, 0);

        // Store: node = tile*128 + tn*16 + l15; f = f_base + tm*16 + lhi*4 + i
#pragma unroll
        for (int tm = 0; tm < 2; ++tm) {
            int f0 = f_base + tm * 16 + lhi * 4;
#pragma unroll
            for (int tn = 0; tn < 8; ++tn) {
                int node = tile * 128 + tn * 16 + l15;
                bf16x4_t o;
                o.x = (bf16_t)acc[tm][tn][0];
                o.y = (bf16_t)acc[tm][tn][1];
                o.z = (bf16_t)acc[tm][tn][2];
                o.w = (bf16_t)acc[tm][tn][3];
                *reinterpret_cast<bf16x4_t*>(hall + ((size_t)node * NRELS + r) * FEAT + f0) = o;
            }
        }
    }
}

// ---------------------------------------------------------------------------
// CSR build
__global__ void k_degree(const int* __restrict__ dstv, int* __restrict__ deg, int nedges) {
    int e = blockIdx.x * blockDim.x + threadIdx.x;
    if (e >= nedges) return;
    atomicAdd(&deg[dstv[e]], 1);
}

// One 256-wide chunk per block: in-block inclusive scan -> exclusive out + block sum.
__global__ __launch_bounds__(256) void k_scan_block(const int* __restrict__ in,
                                                    int* __restrict__ outv,
                                                    int* __restrict__ bsum, int n) {
    __shared__ int sm[256];
    int t = threadIdx.x;
    int idx = blockIdx.x * SCAN_CHUNK + t;
    int v = (idx < n) ? in[idx] : 0;
    sm[t] = v;
    __syncthreads();
    for (int off = 1; off < 256; off <<= 1) {
        int x = (t >= off) ? sm[t - off] : 0;
        __syncthreads();
        sm[t] += x;
        __syncthreads();
    }
    if (idx < n) outv[idx] = sm[t] - v;
    if (t == 255) bsum[blockIdx.x] = sm[255];
}

// Scan the block sums (nb <= 1024 fast path; serial fallback beyond).
__global__ __launch_bounds__(1024) void k_scan_tops(int* __restrict__ bsum, int nb,
                                                    int* __restrict__ rowptr_end) {
    __shared__ int sm[1024];
    int t = threadIdx.x;
    if (nb <= 1024) {
        int v = (t < nb) ? bsum[t] : 0;
        sm[t] = v;
        __syncthreads();
        for (int off = 1; off < 1024; off <<= 1) {
            int x = (t >= off) ? sm[t - off] : 0;
            __syncthreads();
            sm[t] += x;
            __syncthreads();
        }
        if (t < nb) bsum[t] = sm[t] - v;
        if (t == 1023) *rowptr_end = sm[1023];
    } else if (t == 0) {
        int run = 0;
        for (int b = 0; b < nb; ++b) { int v = bsum[b]; bsum[b] = run; run += v; }
        *rowptr_end = run;
    }
}

__global__ void k_scan_add(int* __restrict__ rowptr, const int* __restrict__ bsum, int n) {
    int i = blockIdx.x * blockDim.x + threadIdx.x;
    if (i >= n) return;
    rowptr[i] += bsum[i >> 8];   // 256 = 1<<8
}

// Fill packed edge records {hall_row, norm*sigmoid_gate} at CSR slots.
__global__ void k_fill(const int* __restrict__ src, const int* __restrict__ dstv,
                       const int* __restrict__ rel, const float* __restrict__ nrm,
                       const float* __restrict__ sg, const int* __restrict__ rowptr,
                       int* __restrict__ cursor, PackedEdge* __restrict__ packed,
                       int nedges) {
    int e = blockIdx.x * blockDim.x + threadIdx.x;
    if (e >= nedges) return;
    int d = dstv[e];
    int s = src[e];
    int r = rel[e];
    int pos = rowptr[d] + atomicAdd(&cursor[d], 1);
    PackedEdge p;
    p.row = s * NRELS + r;
    p.scale = nrm[e] * sg[(size_t)s * NRELS + r];
    packed[pos] = p;
}

// ---------------------------------------------------------------------------
// Gather: one wave per dst node, 2 edges per iteration (half-wave each:
// 32 lanes x bf16x4 = one 256B hall row). Combine halves via shfl_xor(32).
__global__ __launch_bounds__(256) void k_gather(const bf16_t* __restrict__ hall,
                                                const PackedEdge* __restrict__ packed,
                                                const int* __restrict__ rowptr,
                                                float* __restrict__ out, int nnodes) {
    int wv = (int)((blockIdx.x * blockDim.x + threadIdx.x) >> 6);
    int lane = threadIdx.x & 63;
    if (wv >= nnodes) return;
    int half = lane >> 5;        // 0: even edges, 1: odd edges
    int sub = lane & 31;         // feature group: feats [sub*4, sub*4+4)
    int beg = rowptr[wv];
    int end = rowptr[wv + 1];
    float ax = 0.f, ay = 0.f, az = 0.f, aw = 0.f;
    int j = beg + half;
    PackedEdge p;
    if (j < end) p = packed[j];
#pragma unroll 1
    for (; j < end; j += 2) {
        PackedEdge pn;
        if (j + 2 < end) pn = packed[j + 2];     // prefetch next record
        bf16x4_t mv = *reinterpret_cast<const bf16x4_t*>(
            hall + (size_t)p.row * FEAT + sub * 4);
        ax += (float)mv.x * p.scale;
        ay += (float)mv.y * p.scale;
        az += (float)mv.z * p.scale;
        aw += (float)mv.w * p.scale;
        p = pn;
    }
    ax += __shfl_xor(ax, 32);
    ay += __shfl_xor(ay, 32);
    az += __shfl_xor(az, 32);
    aw += __shfl_xor(aw, 32);
    if (half == 0) {
        float4 o;
        o.x = fmaxf(ax, 0.f);
        o.y = fmaxf(ay, 0.f);
        o.z = fmaxf(az, 0.f);
        o.w = fmaxf(aw, 0.f);
        *reinterpret_cast<float4*>(out + (size_t)wv * FEAT + sub * 4) = o;
    }
}

// ---------------------------------------------------------------------------
// Fallback path (small ws): chunked atomic scatter
__global__ __launch_bounds__(256) void k_scatter(const bf16_t* __restrict__ hall,
                                                 const float* __restrict__ sg,
                                                 const float* __restrict__ nrm,
                                                 const int* __restrict__ src,
                                                 const int* __restrict__ dstv,
                                                 const int* __restrict__ rel,
                                                 float* __restrict__ out,
                                                 int node0, int ncount, int nedges) {
    int e = (int)((blockIdx.x * blockDim.x + threadIdx.x) >> 6);
    if (e >= nedges) return;
    int lane = threadIdx.x & 63;
    int s = src[e] - node0;
    if ((unsigned)s >= (unsigned)ncount) return;
    int r = rel[e];
    float scale = nrm[e] * sg[(size_t)s * NRELS + r];
    bf16x2_t mv = *reinterpret_cast<const bf16x2_t*>(
        hall + ((size_t)s * NRELS + r) * FEAT + lane * 2);
    float* op = out + (size_t)dstv[e] * FEAT + lane * 2;
    unsafeAtomicAdd(op, (float)mv.x * scale);
    unsafeAtomicAdd(op + 1, (float)mv.y * scale);
}

__global__ void k_relu(float4* __restrict__ out, int total4) {
    int i = blockIdx.x * blockDim.x + threadIdx.x;
    if (i >= total4) return;
    float4 v = out[i];
    v.x = fmaxf(v.x, 0.f);
    v.y = fmaxf(v.y, 0.f);
    v.z = fmaxf(v.z, 0.f);
    v.w = fmaxf(v.w, 0.f);
    out[i] = v;
}

// ---------------------------------------------------------------------------
extern "C" void kernel_launch(void* const* d_in, const int* in_sizes, int n_in,
                              void* d_out, int out_size, void* d_ws, size_t ws_size,
                              hipStream_t stream) {
    const float* h = (const float*)d_in[0];
    const float* w = (const float*)d_in[1];
    const float* gw = (const float*)d_in[2];
    const float* nrm = (const float*)d_in[3];
    const int* src = (const int*)d_in[4];
    const int* dst = (const int*)d_in[5];
    const int* rel = (const int*)d_in[6];
    float* out = (float*)d_out;

    const int N = in_sizes[0] / FEAT;
    const int E = in_sizes[4];
    const int Nceil = ((N + 127) / 128) * 128;
    const int nb = (N + SCAN_CHUNK - 1) / SCAN_CHUNK;

    char* ws = (char*)d_ws;
    const size_t wtB = (size_t)NRELS * FEAT * FEAT * sizeof(bf16_t);      // 256 KiB
    const size_t hallB = (size_t)Nceil * NRELS * FEAT * sizeof(bf16_t);   // 205 MB
    const size_t hbB = (size_t)Nceil * FEAT * sizeof(bf16_t);             // 25.6 MB
    // CSR block (aliases hb region; lifetimes disjoint: built after GEMM)
    const size_t sgB = align256((size_t)N * NRELS * sizeof(float));
    const size_t degB = align256((size_t)N * sizeof(int));
    const size_t rowB = align256((size_t)(N + 1) * sizeof(int));
    const size_t bsB = align256((size_t)nb * sizeof(int));
    const size_t pkB = align256((size_t)E * sizeof(PackedEdge));
    const size_t csrB = sgB + degB + rowB + bsB + pkB;
    const size_t tailNeed = hbB > csrB ? hbB : csrB;

    if (wtB + hallB + tailNeed <= ws_size) {
        // ------------------ full-graph CSR path ------------------
        bf16_t* wt = (bf16_t*)ws;
        bf16_t* hall = (bf16_t*)(ws + wtB);
        char* tail = ws + wtB + hallB;
        bf16_t* hb = (bf16_t*)tail;                       // dead after GEMM
        float* sg = (float*)tail;
        int* deg = (int*)(tail + sgB);
        int* rowptr = (int*)(tail + sgB + degB);
        int* bsum = (int*)(tail + sgB + degB + rowB);
        PackedEdge* packed = (PackedEdge*)(tail + sgB + degB + rowB + bsB);

        k_convert_w<<<(NRELS * FEAT * FEAT + 255) / 256, 256, 0, stream>>>(w, wt);
        k_convert_h<<<(Nceil * (FEAT / 4) + 255) / 256, 256, 0, stream>>>(h, (bf16x4_t*)hb, 0, N, Nceil);
        k_gemm8<<<Nceil / 128, 256, 0, stream>>>(hb, wt, hall);
        // hb dead from here; CSR block aliases it
        k_gate<<<(N + 3) / 4, 256, 0, stream>>>(h, gw, sg, 0, N);
        hipMemsetAsync(deg, 0, (size_t)N * sizeof(int), stream);
        k_degree<<<(E + 255) / 256, 256, 0, stream>>>(dst, deg, E);
        k_scan_block<<<nb, 256, 0, stream>>>(deg, rowptr, bsum, N);
        k_scan_tops<<<1, 1024, 0, stream>>>(bsum, nb, rowptr + N);
        k_scan_add<<<(N + 255) / 256, 256, 0, stream>>>(rowptr, bsum, N);
        hipMemsetAsync(deg, 0, (size_t)N * sizeof(int), stream);          // reuse as cursor
        k_fill<<<(E + 255) / 256, 256, 0, stream>>>(src, dst, rel, nrm, sg, rowptr, deg, packed, E);
        k_gather<<<(N + 3) / 4, 256, 0, stream>>>(hall, packed, rowptr, out, N);
    } else {
        // ------------------ chunked atomic fallback ------------------
        bf16_t* wt = (bf16_t*)ws;
        const size_t per_node = FEAT * sizeof(bf16_t) + NRELS * sizeof(float)
                              + (size_t)NRELS * FEAT * sizeof(bf16_t);
        size_t avail = ws_size > wtB ? ws_size - wtB : 0;
        long long cmax = (long long)(avail / per_node);
        int C = (int)((cmax / 128) * 128);
        if (C > Nceil) C = Nceil;
        if (C < 128) C = 128;
        bf16_t* hb = (bf16_t*)(ws + wtB);
        float* sg = (float*)(ws + wtB + (size_t)C * FEAT * sizeof(bf16_t));
        bf16_t* hall = (bf16_t*)((char*)sg + (size_t)C * NRELS * sizeof(float));

        hipMemsetAsync(d_out, 0, (size_t)N * FEAT * sizeof(float), stream);
        k_convert_w<<<(NRELS * FEAT * FEAT + 255) / 256, 256, 0, stream>>>(w, wt);
        for (int node0 = 0; node0 < N; node0 += C) {
            int nc = N - node0;
            if (nc > C) nc = C;
            int ncceil = ((nc + 127) / 128) * 128;
            k_convert_h<<<(ncceil * (FEAT / 4) + 255) / 256, 256, 0, stream>>>(
                h, (bf16x4_t*)hb, node0, nc, ncceil);
            k_gate<<<(nc + 3) / 4, 256, 0, stream>>>(h, gw, sg, node0, nc);
            k_gemm8<<<ncceil / 128, 256, 0, stream>>>(hb, wt, hall);
            k_scatter<<<(E + 3) / 4, 256, 0, stream>>>(hall, sg, nrm, src, dst, rel, out,
                                                       node0, nc, E);
        }
        k_relu<<<((N * FEAT / 4) + 255) / 256, 256, 0, stream>>>((float4*)out, N * FEAT / 4);
    }
}